// Round 1
// baseline (208.432 us; speedup 1.0000x reference)
//
#include <hip/hip_runtime.h>
#include <cstdint>
#include <cstddef>

// out[8192,2048] = x[8192,2048] @ W[2048,2048]^T + b   (fp32 in/out)
// Strategy: convert x,W -> bf16 in d_ws, then 128x128-tile MFMA GEMM
// (m97 structure: global_load_lds width=16, 16x16x32 bf16 MFMA, 4 waves).

#define MM 8192
#define NN 2048
#define KK 2048

typedef __attribute__((ext_vector_type(8))) short bf16x8;
typedef __attribute__((ext_vector_type(4))) float f32x4;

struct alignas(16) us8 { unsigned short v[8]; };

__device__ inline unsigned short f2bf(float f) {
  union { float f; unsigned u; } x; x.f = f;
  unsigned u = x.u;
  unsigned r = (u + 0x7fffu + ((u >> 16) & 1u)) >> 16;  // RNE
  return (unsigned short)r;
}

__global__ void cvt_kernel(const float* __restrict__ in,
                           unsigned short* __restrict__ out, int nchunks) {
  int idx = blockIdx.x * blockDim.x + threadIdx.x;
  int stride = gridDim.x * blockDim.x;
  for (int c = idx; c < nchunks; c += stride) {
    float4 a = ((const float4*)in)[2 * c];
    float4 b = ((const float4*)in)[2 * c + 1];
    us8 o;
    o.v[0] = f2bf(a.x); o.v[1] = f2bf(a.y); o.v[2] = f2bf(a.z); o.v[3] = f2bf(a.w);
    o.v[4] = f2bf(b.x); o.v[5] = f2bf(b.y); o.v[6] = f2bf(b.z); o.v[7] = f2bf(b.w);
    ((us8*)out)[c] = o;
  }
}

// A: [M][K] bf16 row-major, B: [N][K] bf16 row-major (i.e. B^T layout), C fp32.
__global__ __launch_bounds__(256, 2) void gemm_bf16_kernel(
    const unsigned short* __restrict__ A,
    const unsigned short* __restrict__ B,
    const float* __restrict__ bias,
    float* __restrict__ C) {
  constexpr int BM = 128, BN = 128, BK = 32;
  __shared__ unsigned short sA[BM * BK];
  __shared__ unsigned short sB[BN * BK];

  const int tid = threadIdx.x;
  const int lane = tid & 63;
  const int w = tid >> 6;      // wave 0..3
  const int wr = w >> 1;       // wave row 0..1 (64 rows each)
  const int wc = w & 1;        // wave col 0..1 (64 cols each)

  const int bcol = blockIdx.x * BN;
  const int brow = blockIdx.y * BM;

  f32x4 acc[4][4] = {};

  const unsigned short* Abase = A + (size_t)brow * KK;
  const unsigned short* Bbase = B + (size_t)bcol * KK;

  const int r  = lane & 15;         // fragment row/col
  const int ks = (lane >> 4) * 8;   // fragment k-offset

  for (int k0 = 0; k0 < KK; k0 += BK) {
    // Stage A and B tiles: 512 chunks of 16B each per tile, 2 per thread.
    // LDS dest = wave-uniform base + lane*16 (linear layout requirement).
#pragma unroll
    for (int it = 0; it < 2; ++it) {
      int c = tid + it * 256;         // chunk id 0..511
      int row = c >> 2;               // 4 chunks per 32-elem row
      int col = (c & 3) * 8;
      __builtin_amdgcn_global_load_lds(
          (const __attribute__((address_space(1))) void*)(Abase + (size_t)row * KK + k0 + col),
          (__attribute__((address_space(3))) void*)(&sA[c * 8]), 16, 0, 0);
      __builtin_amdgcn_global_load_lds(
          (const __attribute__((address_space(1))) void*)(Bbase + (size_t)row * KK + k0 + col),
          (__attribute__((address_space(3))) void*)(&sB[c * 8]), 16, 0, 0);
    }
    __syncthreads();   // drains vmcnt+lgkmcnt

    bf16x8 af[4], bfr[4];
#pragma unroll
    for (int mi = 0; mi < 4; ++mi)
      af[mi] = *(const bf16x8*)&sA[(wr * 64 + mi * 16 + r) * BK + ks];
#pragma unroll
    for (int ni = 0; ni < 4; ++ni)
      bfr[ni] = *(const bf16x8*)&sB[(wc * 64 + ni * 16 + r) * BK + ks];

#pragma unroll
    for (int mi = 0; mi < 4; ++mi)
#pragma unroll
      for (int ni = 0; ni < 4; ++ni)
        acc[mi][ni] = __builtin_amdgcn_mfma_f32_16x16x32_bf16(
            af[mi], bfr[ni], acc[mi][ni], 0, 0, 0);

    __syncthreads();   // protect LDS before next-stage overwrite
  }

  // Epilogue: C/D layout col=lane&15, row=(lane>>4)*4+j (m89/m91 verified).
  const int ccol = lane & 15;
  const int crow = (lane >> 4) * 4;
#pragma unroll
  for (int ni = 0; ni < 4; ++ni) {
    float bv = bias[bcol + wc * 64 + ni * 16 + ccol];
#pragma unroll
    for (int mi = 0; mi < 4; ++mi) {
      size_t rowg = (size_t)brow + wr * 64 + mi * 16 + crow;
      float* cp = C + rowg * NN + bcol + wc * 64 + ni * 16 + ccol;
#pragma unroll
      for (int j = 0; j < 4; ++j)
        cp[(size_t)j * NN] = acc[mi][ni][j] + bv;
    }
  }
}

// Correct-but-slow fp32 fallback in case ws_size < 40MB (unlikely).
__global__ void gemm_fallback(const float* __restrict__ X, const float* __restrict__ W,
                              const float* __restrict__ bias, float* __restrict__ out) {
  __shared__ float xs[512];
  int row = blockIdx.y;
  int col = blockIdx.x * 256 + threadIdx.x;
  float s = 0.f;
  for (int k0 = 0; k0 < KK; k0 += 512) {
    for (int t = threadIdx.x; t < 512; t += 256) xs[t] = X[(size_t)row * KK + k0 + t];
    __syncthreads();
    for (int k = 0; k < 512; ++k) s += xs[k] * W[(size_t)col * KK + k0 + k];
    __syncthreads();
  }
  out[(size_t)row * NN + col] = s + bias[col];
}

extern "C" void kernel_launch(void* const* d_in, const int* in_sizes, int n_in,
                              void* d_out, int out_size, void* d_ws, size_t ws_size,
                              hipStream_t stream) {
  const float* x    = (const float*)d_in[0];
  const float* wgt  = (const float*)d_in[1];
  const float* bias = (const float*)d_in[2];
  float* out = (float*)d_out;

  const size_t need = ((size_t)MM * KK + (size_t)NN * KK) * sizeof(unsigned short);
  if (ws_size >= need) {
    unsigned short* xb = (unsigned short*)d_ws;
    unsigned short* wb = xb + (size_t)MM * KK;
    cvt_kernel<<<2048, 256, 0, stream>>>(x, xb, MM * KK / 8);
    cvt_kernel<<<1024, 256, 0, stream>>>(wgt, wb, NN * KK / 8);
    dim3 grid(NN / 128, MM / 128);
    gemm_bf16_kernel<<<grid, 256, 0, stream>>>(xb, wb, bias, out);
  } else {
    dim3 grid(NN / 256, MM);
    gemm_fallback<<<grid, 256, 0, stream>>>(x, wgt, bias, out);
  }
}

// Round 3
// 194.933 us; speedup vs baseline: 1.0693x; 1.0693x over previous
//
#include <hip/hip_runtime.h>
#include <cstdint>
#include <cstddef>

// out[8192,2048] = x[8192,2048] @ W[2048,2048]^T + b   (fp32 in/out)
// Round 2 (resubmit): fused cvt kernel + 256x256 ring-pipelined bf16 MFMA GEMM
// (BK=32, 4 LDS stages, counted vmcnt(8), T2 XOR-swizzle, T5 setprio).

#define MM 8192
#define NN 2048
#define KK 2048

typedef __attribute__((ext_vector_type(8))) short bf16x8;
typedef __attribute__((ext_vector_type(4))) float f32x4;

__device__ __forceinline__ unsigned int f2bf(float f) {
  union { float f; unsigned u; } x; x.f = f;
  unsigned u = x.u;
  return (u + 0x7fffu + ((u >> 16) & 1u)) >> 16;  // RNE
}

// Convert both x and W fp32 -> bf16 in one launch (saves a launch + overhead).
__global__ void cvt_both_kernel(const float* __restrict__ x, const float* __restrict__ w,
                                unsigned short* __restrict__ xb, unsigned short* __restrict__ wb) {
  const int XCH = MM * KK / 8;        // x chunks of 8 elems
  const int TCH = XCH + NN * KK / 8;  // + W chunks
  int idx = blockIdx.x * blockDim.x + threadIdx.x;
  int stride = gridDim.x * blockDim.x;
  for (int c = idx; c < TCH; c += stride) {
    const float* src; unsigned short* dst; int cc;
    if (c < XCH) { src = x; dst = xb; cc = c; }
    else         { src = w; dst = wb; cc = c - XCH; }
    float4 a = ((const float4*)src)[2 * cc];
    float4 b = ((const float4*)src)[2 * cc + 1];
    uint4 o;
    o.x = f2bf(a.x) | (f2bf(a.y) << 16);
    o.y = f2bf(a.z) | (f2bf(a.w) << 16);
    o.z = f2bf(b.x) | (f2bf(b.y) << 16);
    o.w = f2bf(b.z) | (f2bf(b.w) << 16);
    ((uint4*)dst)[cc] = o;
  }
}

// A: [M][K] bf16, B: [N][K] bf16 (B^T layout), C fp32 [M][N].
// 8 waves = 2(M) x 4(N); per-wave output 128x64; acc[8][4] f32x4.
// LDS: 4 stages x (A 256x32 + B 256x32) bf16 = 128 KiB (dynamic).
// Swizzle: storage byte = (r*64 + u*16) ^ ((r&7)<<4)  (bijective, 16B-granular).
// global_load_lds dest stays LINEAR; source address carries the inverse swizzle.
__global__ __launch_bounds__(512, 2) void gemm_bf16_ring(
    const unsigned short* __restrict__ A,
    const unsigned short* __restrict__ B,
    const float* __restrict__ bias,
    float* __restrict__ C) {
  constexpr int BM = 256, BN = 256, BK = 32;
  constexpr int NT = KK / BK;            // 64 K-tiles
  constexpr int TA = BM * BK;            // 8192 elems per A stage
  extern __shared__ unsigned short smem[];
  unsigned short* sA = smem;             // 4 * TA
  unsigned short* sB = smem + 4 * TA;    // 4 * TA

  const int tid  = threadIdx.x;
  const int lane = tid & 63;
  const int w    = tid >> 6;     // 0..7
  const int wr   = w >> 2;       // 0..1  (128 rows each)
  const int wc   = w & 3;        // 0..3  (64 cols each)
  const int brow = blockIdx.y * BM;
  const int bcol = blockIdx.x * BN;

  // --- staging descriptors: 2 chunks (16B each) per thread per matrix ---
  // chunk c -> linear LDS byte c*16; logical (row r, 16B-unit u) from the
  // inverse swizzle so that reads with byte^((r&7)<<4) see linear data.
  const int c0 = tid, c1 = 512 + tid;
  const int r0 = ((c0 >> 2) & ~1) | (((c0 >> 2) ^ (c0 >> 4)) & 1);
  const int u0 = (c0 ^ (r0 & 7)) & 3;
  const int r1 = ((c1 >> 2) & ~1) | (((c1 >> 2) ^ (c1 >> 4)) & 1);
  const int u1 = (c1 ^ (r1 & 7)) & 3;
  const unsigned short* a_src0 = A + (size_t)(brow + r0) * KK + u0 * 8;
  const unsigned short* a_src1 = A + (size_t)(brow + r1) * KK + u1 * 8;
  const unsigned short* b_src0 = B + (size_t)(bcol + r0) * KK + u0 * 8;
  const unsigned short* b_src1 = B + (size_t)(bcol + r1) * KK + u1 * 8;

#define STAGE(KT, SLOT) do {                                                        \
    const int _ko = (KT) * BK;                                                      \
    unsigned short* _sa = sA + (SLOT) * TA;                                         \
    unsigned short* _sb = sB + (SLOT) * TA;                                         \
    __builtin_amdgcn_global_load_lds(                                               \
        (const __attribute__((address_space(1))) void*)(a_src0 + _ko),              \
        (__attribute__((address_space(3))) void*)(_sa + c0 * 8), 16, 0, 0);         \
    __builtin_amdgcn_global_load_lds(                                               \
        (const __attribute__((address_space(1))) void*)(a_src1 + _ko),              \
        (__attribute__((address_space(3))) void*)(_sa + c1 * 8), 16, 0, 0);         \
    __builtin_amdgcn_global_load_lds(                                               \
        (const __attribute__((address_space(1))) void*)(b_src0 + _ko),              \
        (__attribute__((address_space(3))) void*)(_sb + c0 * 8), 16, 0, 0);         \
    __builtin_amdgcn_global_load_lds(                                               \
        (const __attribute__((address_space(1))) void*)(b_src1 + _ko),              \
        (__attribute__((address_space(3))) void*)(_sb + c1 * 8), 16, 0, 0);         \
  } while (0)

  // --- fragment read offsets (swizzled), loop-invariant ---
  int a_off[8], b_off[4];
#pragma unroll
  for (int mi = 0; mi < 8; ++mi) {
    int rl = wr * 128 + mi * 16 + (lane & 15);
    a_off[mi] = (rl * 64 + (lane >> 4) * 16) ^ ((lane & 7) << 4);
  }
#pragma unroll
  for (int ni = 0; ni < 4; ++ni) {
    int rl = wc * 64 + ni * 16 + (lane & 15);
    b_off[ni] = (rl * 64 + (lane >> 4) * 16) ^ ((lane & 7) << 4);
  }

  f32x4 acc[8][4] = {};

  // Prologue: prefetch tiles 0,1,2 (12 loads in flight / wave).
  STAGE(0, 0);
  STAGE(1, 1);
  STAGE(2, 2);

  // Per K-tile iteration. vmcnt(8) waits for tile t (oldest 4 loads) while
  // keeping tiles t+1,t+2 in flight. Barrier then publishes tile t to all
  // waves. STAGE(t+3) overwrites the slot all waves finished reading in
  // iteration t-1 (ordered by this barrier) -> race-free.
#define KITER(T, VWSTR, DOSTAGE) do {                                               \
    asm volatile("s_waitcnt vmcnt(" VWSTR ")" ::: "memory");                        \
    __builtin_amdgcn_s_barrier();                                                   \
    asm volatile("" ::: "memory");                                                  \
    if (DOSTAGE) STAGE((T) + 3, ((T) + 3) & 3);                                     \
    const char* _a = (const char*)(sA + ((T) & 3) * TA);                            \
    const char* _b = (const char*)(sB + ((T) & 3) * TA);                            \
    bf16x8 af[8], bfv[4];                                                           \
    _Pragma("unroll") for (int mi = 0; mi < 8; ++mi)                                \
        af[mi] = *(const bf16x8*)(_a + a_off[mi]);                                  \
    _Pragma("unroll") for (int ni = 0; ni < 4; ++ni)                                \
        bfv[ni] = *(const bf16x8*)(_b + b_off[ni]);                                 \
    __builtin_amdgcn_s_setprio(1);                                                  \
    _Pragma("unroll") for (int mi = 0; mi < 8; ++mi)                                \
      _Pragma("unroll") for (int ni = 0; ni < 4; ++ni)                              \
        acc[mi][ni] = __builtin_amdgcn_mfma_f32_16x16x32_bf16(                      \
            af[mi], bfv[ni], acc[mi][ni], 0, 0, 0);                                 \
    __builtin_amdgcn_s_setprio(0);                                                  \
  } while (0)

#pragma unroll 4
  for (int t = 0; t < NT - 3; ++t) KITER(t, "8", 1);
  KITER(NT - 3, "8", 0);   // outstanding: 3 tiles -> waits tile NT-3
  KITER(NT - 2, "4", 0);   // outstanding: 2 tiles -> waits tile NT-2
  KITER(NT - 1, "0", 0);   // last tile: full drain is fine

#undef KITER
#undef STAGE

  // Epilogue. C/D layout: col = lane&15, row = (lane>>4)*4 + j (verified r1).
  const int ccol = lane & 15;
  const int crow = (lane >> 4) * 4;
#pragma unroll
  for (int ni = 0; ni < 4; ++ni) {
    float bv = bias[bcol + wc * 64 + ni * 16 + ccol];
#pragma unroll
    for (int mi = 0; mi < 8; ++mi) {
      size_t rowg = (size_t)brow + wr * 128 + mi * 16 + crow;
      float* cp = C + rowg * NN + bcol + wc * 64 + ni * 16 + ccol;
#pragma unroll
      for (int j = 0; j < 4; ++j)
        cp[(size_t)j * NN] = acc[mi][ni][j] + bv;
    }
  }
}

// Correct-but-slow fp32 fallback in case ws_size < 40MB (unlikely).
__global__ void gemm_fallback(const float* __restrict__ X, const float* __restrict__ W,
                              const float* __restrict__ bias, float* __restrict__ out) {
  __shared__ float xs[512];
  int row = blockIdx.y;
  int col = blockIdx.x * 256 + threadIdx.x;
  float s = 0.f;
  for (int k0 = 0; k0 < KK; k0 += 512) {
    for (int t = threadIdx.x; t < 512; t += 256) xs[t] = X[(size_t)row * KK + k0 + t];
    __syncthreads();
    for (int k = 0; k < 512; ++k) s += xs[k] * W[(size_t)col * KK + k0 + k];
    __syncthreads();
  }
  out[(size_t)row * NN + col] = s + bias[col];
}

extern "C" void kernel_launch(void* const* d_in, const int* in_sizes, int n_in,
                              void* d_out, int out_size, void* d_ws, size_t ws_size,
                              hipStream_t stream) {
  const float* x    = (const float*)d_in[0];
  const float* wgt  = (const float*)d_in[1];
  const float* bias = (const float*)d_in[2];
  float* out = (float*)d_out;

  const size_t need = ((size_t)MM * KK + (size_t)NN * KK) * sizeof(unsigned short);
  if (ws_size >= need) {
    unsigned short* xb = (unsigned short*)d_ws;
    unsigned short* wb = xb + (size_t)MM * KK;
    cvt_both_kernel<<<2048, 256, 0, stream>>>(x, wgt, xb, wb);

    constexpr int lds_bytes = 4 * (256 * 32 + 256 * 32) * 2;  // 128 KiB
    hipFuncSetAttribute((const void*)gemm_bf16_ring,
                        hipFuncAttributeMaxDynamicSharedMemorySize, lds_bytes);
    dim3 grid(NN / 256, MM / 256);  // (8, 32) = 256 blocks = 1/CU
    gemm_bf16_ring<<<grid, 512, lds_bytes, stream>>>(xb, wb, bias, out);
  } else {
    dim3 grid(NN / 256, MM);
    gemm_fallback<<<grid, 256, 0, stream>>>(x, wgt, bias, out);
  }
}

// Round 4
// 194.810 us; speedup vs baseline: 1.0699x; 1.0006x over previous
//
#include <hip/hip_runtime.h>
#include <cstdint>
#include <cstddef>

// out[8192,2048] = x[8192,2048] @ W[2048,2048]^T + b   (fp32 in/out)
// Round 4: same 4-slot ring staging (BK=32, prefetch-3, counted vmcnt) but
// compute split into m201-style fine phases (2 phases/K-tile, 16 MFMA each,
// barrier-pair per phase, setprio around MFMA cluster) + bijective
// XCD-chunked block swizzle (T1).

#define MM 8192
#define NN 2048
#define KK 2048

typedef __attribute__((ext_vector_type(8))) short bf16x8;
typedef __attribute__((ext_vector_type(4))) float f32x4;

__device__ __forceinline__ unsigned int f2bf(float f) {
  union { float f; unsigned u; } x; x.f = f;
  unsigned u = x.u;
  return (u + 0x7fffu + ((u >> 16) & 1u)) >> 16;  // RNE
}

// Convert both x and W fp32 -> bf16 in one launch.
__global__ void cvt_both_kernel(const float* __restrict__ x, const float* __restrict__ w,
                                unsigned short* __restrict__ xb, unsigned short* __restrict__ wb) {
  const int XCH = MM * KK / 8;        // x chunks of 8 elems
  const int TCH = XCH + NN * KK / 8;  // + W chunks
  int idx = blockIdx.x * blockDim.x + threadIdx.x;
  int stride = gridDim.x * blockDim.x;
  for (int c = idx; c < TCH; c += stride) {
    const float* src; unsigned short* dst; int cc;
    if (c < XCH) { src = x; dst = xb; cc = c; }
    else         { src = w; dst = wb; cc = c - XCH; }
    float4 a = ((const float4*)src)[2 * cc];
    float4 b = ((const float4*)src)[2 * cc + 1];
    uint4 o;
    o.x = f2bf(a.x) | (f2bf(a.y) << 16);
    o.y = f2bf(a.z) | (f2bf(a.w) << 16);
    o.z = f2bf(b.x) | (f2bf(b.y) << 16);
    o.w = f2bf(b.z) | (f2bf(b.w) << 16);
    ((uint4*)dst)[cc] = o;
  }
}

// A: [M][K] bf16, B: [N][K] bf16 (B^T layout), C fp32 [M][N].
// 8 waves = 2(M) x 4(N); per-wave output 128x64; acc[8][4] f32x4.
// LDS: 4 ring slots x (A 256x32 + B 256x32) bf16 = 128 KiB (dynamic).
// Swizzle: storage byte = (r*64 + u*16) ^ ((r&7)<<4) (bijective, 16B units).
// global_load_lds dest stays LINEAR; source address carries the inverse.
__global__ __launch_bounds__(512, 2) void gemm_bf16_ring(
    const unsigned short* __restrict__ A,
    const unsigned short* __restrict__ B,
    const float* __restrict__ bias,
    float* __restrict__ C) {
  constexpr int BM = 256, BN = 256, BK = 32;
  constexpr int NT = KK / BK;            // 64 K-tiles
  constexpr int TA = BM * BK;            // 8192 elems per ring slot (per matrix)
  extern __shared__ unsigned short smem[];
  unsigned short* sA = smem;             // 4 * TA
  unsigned short* sB = smem + 4 * TA;    // 4 * TA

  const int tid  = threadIdx.x;
  const int lane = tid & 63;
  const int w    = tid >> 6;     // 0..7
  const int wr   = w >> 2;       // 0..1  (128 rows each)
  const int wc   = w & 3;        // 0..3  (64 cols each)

  // T1: bijective XCD-chunked swizzle. 256 blocks, 8 XCDs, 32 blocks/XCD.
  // XCD x gets logical tiles x*32..x*32+31 = 4 full A-panel rows x 8 B-panels.
  const int l   = blockIdx.x;
  const int lid = (l & 7) * 32 + (l >> 3);
  const int by  = lid >> 3;      // 0..31
  const int bx  = lid & 7;       // 0..7
  const int brow = by * BM;
  const int bcol = bx * BN;

  // --- staging descriptors: 2 chunks (16B each) per thread per matrix ---
  // chunk c -> linear LDS byte c*16; logical (row r, 16B-unit u) from the
  // inverse swizzle so reads at byte^((r&7)<<4) see consistent data.
  const int c0 = tid, c1 = 512 + tid;
  const int r0 = ((c0 >> 2) & ~1) | (((c0 >> 2) ^ (c0 >> 4)) & 1);
  const int u0 = (c0 ^ (r0 & 7)) & 3;
  const int r1 = ((c1 >> 2) & ~1) | (((c1 >> 2) ^ (c1 >> 4)) & 1);
  const int u1 = (c1 ^ (r1 & 7)) & 3;
  const unsigned short* a_src0 = A + (size_t)(brow + r0) * KK + u0 * 8;
  const unsigned short* a_src1 = A + (size_t)(brow + r1) * KK + u1 * 8;
  const unsigned short* b_src0 = B + (size_t)(bcol + r0) * KK + u0 * 8;
  const unsigned short* b_src1 = B + (size_t)(bcol + r1) * KK + u1 * 8;

#define STAGE(KT, SLOT) do {                                                        \
    const int _ko = (KT) * BK;                                                      \
    unsigned short* _sa = sA + (SLOT) * TA;                                         \
    unsigned short* _sb = sB + (SLOT) * TA;                                         \
    __builtin_amdgcn_global_load_lds(                                               \
        (const __attribute__((address_space(1))) void*)(a_src0 + _ko),              \
        (__attribute__((address_space(3))) void*)(_sa + c0 * 8), 16, 0, 0);         \
    __builtin_amdgcn_global_load_lds(                                               \
        (const __attribute__((address_space(1))) void*)(a_src1 + _ko),              \
        (__attribute__((address_space(3))) void*)(_sa + c1 * 8), 16, 0, 0);         \
    __builtin_amdgcn_global_load_lds(                                               \
        (const __attribute__((address_space(1))) void*)(b_src0 + _ko),              \
        (__attribute__((address_space(3))) void*)(_sb + c0 * 8), 16, 0, 0);         \
    __builtin_amdgcn_global_load_lds(                                               \
        (const __attribute__((address_space(1))) void*)(b_src1 + _ko),              \
        (__attribute__((address_space(3))) void*)(_sb + c1 * 8), 16, 0, 0);         \
  } while (0)

  // --- fragment read offsets (swizzled), loop-invariant ---
  int a_off[8], b_off[4];
#pragma unroll
  for (int mi = 0; mi < 8; ++mi) {
    int rl = wr * 128 + mi * 16 + (lane & 15);
    a_off[mi] = (rl * 64 + (lane >> 4) * 16) ^ ((lane & 7) << 4);
  }
#pragma unroll
  for (int ni = 0; ni < 4; ++ni) {
    int rl = wc * 64 + ni * 16 + (lane & 15);
    b_off[ni] = (rl * 64 + (lane >> 4) * 16) ^ ((lane & 7) << 4);
  }

  f32x4 acc[8][4] = {};

  // Prologue: prefetch tiles 0,1,2 (12 loads in flight / wave); publish tile 0.
  STAGE(0, 0);
  STAGE(1, 1);
  STAGE(2, 2);
  asm volatile("s_waitcnt vmcnt(8)" ::: "memory");
  __builtin_amdgcn_s_barrier();

  // Per K-tile iteration, 2 phases of 16 MFMA each (m201 granularity).
  // Tile-t data validity: prev iter's trailing {vmcnt; barrier}.
  // STAGE(t+3) overwrites slot (t-1)&3 whose last reads finished before the
  // prev trailing barrier. Trailing vmcnt retires tile t+1 for the next iter.
#define KITER(T, DOSTAGE, TAILVM) do {                                              \
    const char* _a = (const char*)(sA + ((T) & 3) * TA);                            \
    const char* _b = (const char*)(sB + ((T) & 3) * TA);                            \
    /* ---- phase 1: A-frags m0-3 + all B-frags; stage t+3 ---- */                  \
    if (DOSTAGE) STAGE((T) + 3, ((T) + 3) & 3);                                     \
    bf16x8 af[4], bfv[4];                                                           \
    _Pragma("unroll") for (int mi = 0; mi < 4; ++mi)                                \
        af[mi] = *(const bf16x8*)(_a + a_off[mi]);                                  \
    _Pragma("unroll") for (int ni = 0; ni < 4; ++ni)                                \
        bfv[ni] = *(const bf16x8*)(_b + b_off[ni]);                                 \
    asm volatile("" ::: "memory");                                                  \
    __builtin_amdgcn_s_barrier();                                                   \
    asm volatile("s_waitcnt lgkmcnt(0)" ::: "memory");                              \
    __builtin_amdgcn_sched_barrier(0);                                              \
    __builtin_amdgcn_s_setprio(1);                                                  \
    _Pragma("unroll") for (int mi = 0; mi < 4; ++mi)                                \
      _Pragma("unroll") for (int ni = 0; ni < 4; ++ni)                              \
        acc[mi][ni] = __builtin_amdgcn_mfma_f32_16x16x32_bf16(                      \
            af[mi], bfv[ni], acc[mi][ni], 0, 0, 0);                                 \
    __builtin_amdgcn_s_setprio(0);                                                  \
    __builtin_amdgcn_s_barrier();                                                   \
    /* ---- phase 2: A-frags m4-7 ---- */                                           \
    bf16x8 af2[4];                                                                  \
    _Pragma("unroll") for (int mi = 0; mi < 4; ++mi)                                \
        af2[mi] = *(const bf16x8*)(_a + a_off[4 + mi]);                             \
    asm volatile("" ::: "memory");                                                  \
    __builtin_amdgcn_s_barrier();                                                   \
    asm volatile("s_waitcnt lgkmcnt(0)" ::: "memory");                              \
    __builtin_amdgcn_sched_barrier(0);                                              \
    __builtin_amdgcn_s_setprio(1);                                                  \
    _Pragma("unroll") for (int mi = 0; mi < 4; ++mi)                                \
      _Pragma("unroll") for (int ni = 0; ni < 4; ++ni)                              \
        acc[4 + mi][ni] = __builtin_amdgcn_mfma_f32_16x16x32_bf16(                  \
            af2[mi], bfv[ni], acc[4 + mi][ni], 0, 0, 0);                            \
    __builtin_amdgcn_s_setprio(0);                                                  \
    TAILVM;                                                                         \
    __builtin_amdgcn_s_barrier();                                                   \
  } while (0)

#pragma unroll 4
  for (int t = 0; t < NT - 3; ++t)
    KITER(t, 1, asm volatile("s_waitcnt vmcnt(8)" ::: "memory"));
  KITER(NT - 3, 0, asm volatile("s_waitcnt vmcnt(4)" ::: "memory"));
  KITER(NT - 2, 0, asm volatile("s_waitcnt vmcnt(0)" ::: "memory"));
  KITER(NT - 1, 0, (void)0);

#undef KITER
#undef STAGE

  // Epilogue. C/D layout: col = lane&15, row = (lane>>4)*4 + j (verified r1).
  const int ccol = lane & 15;
  const int crow = (lane >> 4) * 4;
#pragma unroll
  for (int ni = 0; ni < 4; ++ni) {
    float bv = bias[bcol + wc * 64 + ni * 16 + ccol];
#pragma unroll
    for (int mi = 0; mi < 8; ++mi) {
      size_t rowg = (size_t)brow + wr * 128 + mi * 16 + crow;
      float* cp = C + rowg * NN + bcol + wc * 64 + ni * 16 + ccol;
#pragma unroll
      for (int j = 0; j < 4; ++j)
        cp[(size_t)j * NN] = acc[mi][ni][j] + bv;
    }
  }
}

// Correct-but-slow fp32 fallback in case ws_size < 40MB (unlikely).
__global__ void gemm_fallback(const float* __restrict__ X, const float* __restrict__ W,
                              const float* __restrict__ bias, float* __restrict__ out) {
  __shared__ float xs[512];
  int row = blockIdx.y;
  int col = blockIdx.x * 256 + threadIdx.x;
  float s = 0.f;
  for (int k0 = 0; k0 < KK; k0 += 512) {
    for (int t = threadIdx.x; t < 512; t += 256) xs[t] = X[(size_t)row * KK + k0 + t];
    __syncthreads();
    for (int k = 0; k < 512; ++k) s += xs[k] * W[(size_t)col * KK + k0 + k];
    __syncthreads();
  }
  out[(size_t)row * NN + col] = s + bias[col];
}

extern "C" void kernel_launch(void* const* d_in, const int* in_sizes, int n_in,
                              void* d_out, int out_size, void* d_ws, size_t ws_size,
                              hipStream_t stream) {
  const float* x    = (const float*)d_in[0];
  const float* wgt  = (const float*)d_in[1];
  const float* bias = (const float*)d_in[2];
  float* out = (float*)d_out;

  const size_t need = ((size_t)MM * KK + (size_t)NN * KK) * sizeof(unsigned short);
  if (ws_size >= need) {
    unsigned short* xb = (unsigned short*)d_ws;
    unsigned short* wb = xb + (size_t)MM * KK;
    cvt_both_kernel<<<2048, 256, 0, stream>>>(x, wgt, xb, wb);

    constexpr int lds_bytes = 4 * (256 * 32 + 256 * 32) * 2;  // 128 KiB
    hipFuncSetAttribute((const void*)gemm_bf16_ring,
                        hipFuncAttributeMaxDynamicSharedMemorySize, lds_bytes);
    gemm_bf16_ring<<<dim3(256), 512, lds_bytes, stream>>>(xb, wb, bias, out);
  } else {
    dim3 grid(NN / 256, MM);
    gemm_fallback<<<grid, 256, 0, stream>>>(x, wgt, bias, out);
  }
}